// Round 1
// baseline (48.996 us; speedup 1.0000x reference)
//
#include <hip/hip_runtime.h>

#define IN_F   8192
#define OUT_F  8192
#define W_THRESH 50.0f
#define INHIB  0.5f

// ---------------------------------------------------------------------------
// Kernel 1: current[o] = sum_i spike[i] * (state[o][i] > 50)
// One wave (64 lanes) per output row; 4 rows per 256-thread block.
// spike_input staged once per block into LDS (32 KB) and shared by all 4 waves.
// ---------------------------------------------------------------------------
__global__ __launch_bounds__(256) void snn_current_kernel(
    const float* __restrict__ spike,
    const float* __restrict__ states,
    float* __restrict__ current)
{
    __shared__ float4 s_spike[IN_F / 4];   // 2048 float4 = 32 KB

    const int tid = threadIdx.x;

    // stage spikes: 256 threads x 8 float4 each, coalesced
    {
        const float4* sp4 = (const float4*)spike;
        #pragma unroll
        for (int k = 0; k < 8; ++k) {
            s_spike[tid + k * 256] = sp4[tid + k * 256];
        }
    }
    __syncthreads();

    const int wave = tid >> 6;            // 0..3
    const int lane = tid & 63;
    const int row  = blockIdx.x * 4 + wave;

    const float4* row4 = (const float4*)(states + (size_t)row * IN_F);

    float acc = 0.0f;
    // 2048 float4 per row / 64 lanes = 32 iterations; coalesced (lanes adjacent)
    #pragma unroll 8
    for (int j = 0; j < 32; ++j) {
        const int idx = j * 64 + lane;
        float4 s  = row4[idx];
        float4 sp = s_spike[idx];
        acc += (s.x > W_THRESH) ? sp.x : 0.0f;
        acc += (s.y > W_THRESH) ? sp.y : 0.0f;
        acc += (s.z > W_THRESH) ? sp.z : 0.0f;
        acc += (s.w > W_THRESH) ? sp.w : 0.0f;
    }

    // 64-lane butterfly reduction
    #pragma unroll
    for (int off = 32; off >= 1; off >>= 1)
        acc += __shfl_down(acc, off, 64);

    if (lane == 0) current[row] = acc;
}

// ---------------------------------------------------------------------------
// Kernel 2: everything else, fused in ONE block (so sum(spikes) needs no
// cross-block sync). 1024 threads x 8 elements each = 8192 outputs.
// out layout: [spikes(8192) | v_mem_new(8192) | v_th_new(8192)]
// ---------------------------------------------------------------------------
__global__ __launch_bounds__(1024) void snn_update_kernel(
    const float* __restrict__ current,
    const float* __restrict__ v_mem,
    const float* __restrict__ v_th,
    const float* __restrict__ noise,
    float* __restrict__ out)
{
    __shared__ float s_partial[16];
    __shared__ float s_total;

    const int tid = threadIdx.x;

    float cur[8], spk[8], vm[8], vt[8];
    float local = 0.0f;

    #pragma unroll
    for (int k = 0; k < 8; ++k) {
        const int o = tid + k * 1024;
        const float c = current[o];
        const float m = v_mem[o];
        const float t = v_th[o];
        const float n = noise[o];
        const float pot = m + c + n;
        const float s = (pot >= t) ? 1.0f : 0.0f;
        cur[k] = c; spk[k] = s; vm[k] = m; vt[k] = t;
        local += s;
    }

    // wave reduce (64 lanes)
    #pragma unroll
    for (int off = 32; off >= 1; off >>= 1)
        local += __shfl_down(local, off, 64);

    if ((tid & 63) == 0) s_partial[tid >> 6] = local;
    __syncthreads();

    if (tid == 0) {
        float tot = 0.0f;
        #pragma unroll
        for (int w = 0; w < 16; ++w) tot += s_partial[w];
        s_total = tot;
    }
    __syncthreads();

    const float inhibition = s_total * INHIB;

    #pragma unroll
    for (int k = 0; k < 8; ++k) {
        const int o = tid + k * 1024;
        out[o] = spk[k];
        const float vnew = (vm[k] - inhibition + cur[k]) * (1.0f - spk[k]) * 0.5f;
        out[OUT_F + o] = vnew;
        float tnew = vt[k] + (spk[k] - 0.1f) * 0.01f;
        tnew = fminf(fmaxf(tnew, 0.2f), 5.0f);
        out[2 * OUT_F + o] = tnew;
    }
}

// ---------------------------------------------------------------------------
extern "C" void kernel_launch(void* const* d_in, const int* in_sizes, int n_in,
                              void* d_out, int out_size, void* d_ws, size_t ws_size,
                              hipStream_t stream)
{
    const float* spike  = (const float*)d_in[0];  // [1, 8192]
    const float* states = (const float*)d_in[1];  // [8192, 8192]
    const float* v_mem  = (const float*)d_in[2];  // [8192]
    const float* v_th   = (const float*)d_in[3];  // [8192]
    const float* noise  = (const float*)d_in[4];  // [8192]
    float* out = (float*)d_out;                   // [3 * 8192]

    float* current = (float*)d_ws;                // 8192 floats = 32 KB scratch

    snn_current_kernel<<<OUT_F / 4, 256, 0, stream>>>(spike, states, current);
    snn_update_kernel<<<1, 1024, 0, stream>>>(current, v_mem, v_th, noise, out);
}

// Round 2
// 46.419 us; speedup vs baseline: 1.0555x; 1.0555x over previous
//
#include <hip/hip_runtime.h>

#define IN_F   8192
#define OUT_F  8192
#define W_THRESH 50.0f
#define INHIB  0.5f

typedef float f32x4 __attribute__((ext_vector_type(4)));

// ---------------------------------------------------------------------------
// Kernel 1: current[o] = sum_i spike[i] * (state[o][i] > 50), then the per-row
// spike decision (needs only row-local scalars) fused into the epilogue.
// One wave per output row; 4 rows per 256-thread block; spikes staged in LDS.
// States streamed with nontemporal loads (read exactly once, 268 MB).
// ---------------------------------------------------------------------------
__global__ __launch_bounds__(256) void snn_current_kernel(
    const float* __restrict__ spike,
    const float* __restrict__ states,
    const float* __restrict__ v_mem,
    const float* __restrict__ v_th,
    const float* __restrict__ noise,
    float* __restrict__ current,      // ws[0..8191]
    float* __restrict__ out_spikes)   // out[0..8191]
{
    __shared__ f32x4 s_spike[IN_F / 4];   // 2048 x 16 B = 32 KB

    const int tid = threadIdx.x;

    // stage spikes: 256 threads x 8 float4 each, coalesced
    {
        const f32x4* sp4 = (const f32x4*)spike;
        #pragma unroll
        for (int k = 0; k < 8; ++k)
            s_spike[tid + k * 256] = sp4[tid + k * 256];
    }
    __syncthreads();

    const int wave = tid >> 6;            // 0..3
    const int lane = tid & 63;
    const int row  = blockIdx.x * 4 + wave;

    const f32x4* row4 = (const f32x4*)(states + (size_t)row * IN_F);

    float acc = 0.0f;
    // 2048 float4 per row / 64 lanes = 32 iterations; lanes adjacent -> coalesced
    #pragma unroll 8
    for (int j = 0; j < 32; ++j) {
        const int idx = j * 64 + lane;
        f32x4 s  = __builtin_nontemporal_load(row4 + idx);
        f32x4 sp = s_spike[idx];
        acc += (s[0] > W_THRESH) ? sp[0] : 0.0f;
        acc += (s[1] > W_THRESH) ? sp[1] : 0.0f;
        acc += (s[2] > W_THRESH) ? sp[2] : 0.0f;
        acc += (s[3] > W_THRESH) ? sp[3] : 0.0f;
    }

    // 64-lane butterfly reduction
    #pragma unroll
    for (int off = 32; off >= 1; off >>= 1)
        acc += __shfl_down(acc, off, 64);

    if (lane == 0) {
        const float c = acc;
        const float pot = v_mem[row] + c + noise[row];
        const float s = (pot >= v_th[row]) ? 1.0f : 0.0f;
        current[row]    = c;
        out_spikes[row] = s;
    }
}

// ---------------------------------------------------------------------------
// Kernel 2: v_mem / v_th updates. Fully parallel: each block redundantly
// reduces all 8192 spikes (32 KB, L2-resident) to get sum(spikes) without
// atomics or an init kernel, then handles its 256-element slice.
// out layout: [spikes(8192) | v_mem_new(8192) | v_th_new(8192)]
// ---------------------------------------------------------------------------
__global__ __launch_bounds__(256) void snn_update_kernel(
    const float* __restrict__ current,
    const float* __restrict__ v_mem,
    const float* __restrict__ v_th,
    const float* __restrict__ spikes,   // == out[0..8191], written by kernel 1
    float* __restrict__ out)
{
    __shared__ float s_part[4];

    const int tid = threadIdx.x;

    // block-wide exact integer sum of all 8192 spike flags
    const f32x4* sp4 = (const f32x4*)spikes;
    float local = 0.0f;
    #pragma unroll
    for (int k = 0; k < 8; ++k) {
        f32x4 v = sp4[tid + k * 256];
        local += v[0] + v[1] + v[2] + v[3];
    }
    #pragma unroll
    for (int off = 32; off >= 1; off >>= 1)
        local += __shfl_down(local, off, 64);
    if ((tid & 63) == 0) s_part[tid >> 6] = local;
    __syncthreads();

    const float total = s_part[0] + s_part[1] + s_part[2] + s_part[3];
    const float inhibition = total * INHIB;

    const int o = blockIdx.x * 256 + tid;
    const float s = spikes[o];
    const float vnew = (v_mem[o] - inhibition + current[o]) * (1.0f - s) * 0.5f;
    out[OUT_F + o] = vnew;
    float tnew = v_th[o] + (s - 0.1f) * 0.01f;
    tnew = fminf(fmaxf(tnew, 0.2f), 5.0f);
    out[2 * OUT_F + o] = tnew;
}

// ---------------------------------------------------------------------------
extern "C" void kernel_launch(void* const* d_in, const int* in_sizes, int n_in,
                              void* d_out, int out_size, void* d_ws, size_t ws_size,
                              hipStream_t stream)
{
    const float* spike  = (const float*)d_in[0];  // [1, 8192]
    const float* states = (const float*)d_in[1];  // [8192, 8192]
    const float* v_mem  = (const float*)d_in[2];  // [8192]
    const float* v_th   = (const float*)d_in[3];  // [8192]
    const float* noise  = (const float*)d_in[4];  // [8192]
    float* out = (float*)d_out;                   // [3 * 8192]

    float* current = (float*)d_ws;                // 8192 floats = 32 KB scratch

    snn_current_kernel<<<OUT_F / 4, 256, 0, stream>>>(
        spike, states, v_mem, v_th, noise, current, out);
    snn_update_kernel<<<OUT_F / 256, 256, 0, stream>>>(
        current, v_mem, v_th, out, out);
}